// Round 1
// baseline (20823.682 us; speedup 1.0000x reference)
//
#include <hip/hip_runtime.h>
#include <hip/hip_bf16.h>

typedef __bf16 bf16;
typedef __bf16 bf16x2 __attribute__((ext_vector_type(2)));
typedef __bf16 bf16x8 __attribute__((ext_vector_type(8)));
typedef float  floatx4 __attribute__((ext_vector_type(4)));

#define NWG 56          // 896/16 column-slices for the scan

// ---------------- workspace layout (bytes) ----------------
// flags: 56 x 128B lines                        = 8,192
// hbuf : bf16 [2][16][896]                      = 57,344
// wbf  : bf16 Wih+Whh+fc1+fc2                   = 13,565,952
// gx   : [T][B][2688] bf16 (h1 aliases after)   = 176,160,768
// hs/x : [32768][896] bf16                      = 58,720,256
static constexpr size_t FL_OFF  = 0;
static constexpr size_t HB_OFF  = 8192;
static constexpr size_t WBF_OFF = 65536;
static constexpr size_t GX_OFF  = WBF_OFF + 13565952;           // 13,631,488
static constexpr size_t HSX_OFF = GX_OFF + 176160768;           // 189,792,256

static constexpr size_t W_IH_E = 2688 * 896;
static constexpr size_t W_HH_E = 2688 * 896;
static constexpr size_t W_F1_E = 1024 * 896;

__device__ __forceinline__ float sigm(float x)      { return 1.f / (1.f + __expf(-x)); }
__device__ __forceinline__ float fast_tanh(float x) { return 2.f / (1.f + __expf(-2.f * x)) - 1.f; }

__device__ __forceinline__ unsigned pack_bf2(float lo, float hi)
{
    union { bf16x2 v; unsigned u; } cv;
    cv.v[0] = (bf16)lo; cv.v[1] = (bf16)hi;
    return cv.u;
}
__device__ __forceinline__ unsigned short bf_bits(float x)
{
    union { bf16 v; unsigned short u; } cv;
    cv.v = (bf16)x;
    return cv.u;
}

// ---------------- f32 -> bf16 conversion (8 elems / thread), exact grids ----------------
__global__ __launch_bounds__(256) void k_cvt(const float* __restrict__ src,
                                             bf16* __restrict__ dst)
{
    const int s = blockIdx.x * 256 + threadIdx.x;
    const float4 a = ((const float4*)src)[s * 2 + 0];
    const float4 b = ((const float4*)src)[s * 2 + 1];
    bf16x8 v;
    v[0] = (bf16)a.x; v[1] = (bf16)a.y; v[2] = (bf16)a.z; v[3] = (bf16)a.w;
    v[4] = (bf16)b.x; v[5] = (bf16)b.y; v[6] = (bf16)b.z; v[7] = (bf16)b.w;
    ((bf16x8*)dst)[s] = v;
}

// ---------------- embed + concat (f32 in, bf16 out) ----------------
__global__ __launch_bounds__(256) void k_embed(const int* __restrict__ samp,
                                               const float* __restrict__ cnd,
                                               const float* __restrict__ emb,
                                               bf16* __restrict__ x)
{
    const int s = blockIdx.x * 256 + threadIdx.x;   // 8-elem segment id; 112 segs/row
    const int r = s / 112;
    const int c = s % 112;
    const float* src;
    if (c < 32) src = emb + samp[r] * 256 + c * 8;
    else        src = cnd + (long)r * 640 + (c - 32) * 8;
    const float4 a = ((const float4*)src)[0];
    const float4 b = ((const float4*)src)[1];
    bf16x8 v;
    v[0] = (bf16)a.x; v[1] = (bf16)a.y; v[2] = (bf16)a.z; v[3] = (bf16)a.w;
    v[4] = (bf16)b.x; v[5] = (bf16)b.y; v[6] = (bf16)b.z; v[7] = (bf16)b.w;
    *(bf16x8*)(x + (long)r * 896 + c * 8) = v;
}

// ---------------- GEMM: C[M,N] = A[M,K] @ Bw[N,K]^T + bias(f32), 128x128 tile, 4 waves ----------
template <int RELU, int GXMODE, int OUTF32>
__global__ __launch_bounds__(256, 2) void gemm_bt(const bf16* __restrict__ A,
                                                  const bf16* __restrict__ Bw,
                                                  const float* __restrict__ bias,
                                                  void* __restrict__ Cv,
                                                  int M, int N, int K)
{
    __shared__ bf16 As[128 * 40];
    __shared__ bf16 Bs[128 * 40];

    const int tid  = threadIdx.x;
    const int lane = tid & 63;
    const int wv   = tid >> 6;
    const int wm   = wv >> 1;
    const int wn   = wv & 1;
    const int n16  = lane & 15;
    const int quad = lane >> 4;
    const int tm   = blockIdx.y * 128;
    const int tn   = blockIdx.x * 128;

    floatx4 acc[4][4] = {};

    const int s0 = tid, s1 = tid + 256;
    const int r0 = s0 >> 2, c0 = s0 & 3;
    const int r1 = s1 >> 2, c1 = s1 & 3;

    const int KT = K >> 5;
    for (int kt = 0; kt < KT; ++kt) {
        const int k0 = kt * 32;
        bf16x8 a0 = *(const bf16x8*)(A  + (long)(tm + r0) * K + k0 + c0 * 8);
        bf16x8 a1 = *(const bf16x8*)(A  + (long)(tm + r1) * K + k0 + c1 * 8);
        bf16x8 b0 = *(const bf16x8*)(Bw + (long)(tn + r0) * K + k0 + c0 * 8);
        bf16x8 b1 = *(const bf16x8*)(Bw + (long)(tn + r1) * K + k0 + c1 * 8);
        __syncthreads();
        *(bf16x8*)(As + r0 * 40 + c0 * 8) = a0;
        *(bf16x8*)(As + r1 * 40 + c1 * 8) = a1;
        *(bf16x8*)(Bs + r0 * 40 + c0 * 8) = b0;
        *(bf16x8*)(Bs + r1 * 40 + c1 * 8) = b1;
        __syncthreads();

        bf16x8 af[4], bfj[4];
#pragma unroll
        for (int i = 0; i < 4; ++i)
            af[i] = *(const bf16x8*)(As + (wm * 64 + i * 16 + n16) * 40 + quad * 8);
#pragma unroll
        for (int j = 0; j < 4; ++j)
            bfj[j] = *(const bf16x8*)(Bs + (wn * 64 + j * 16 + n16) * 40 + quad * 8);
#pragma unroll
        for (int i = 0; i < 4; ++i)
#pragma unroll
            for (int j = 0; j < 4; ++j)
                acc[i][j] = __builtin_amdgcn_mfma_f32_16x16x32_bf16(af[i], bfj[j], acc[i][j], 0, 0, 0);
    }

#pragma unroll
    for (int j = 0; j < 4; ++j) {
        const int c = tn + wn * 64 + j * 16 + n16;
        const float bv = bias[c];
#pragma unroll
        for (int i = 0; i < 4; ++i) {
            const int rbase = tm + wm * 64 + i * 16 + quad * 4;
#pragma unroll
            for (int rr = 0; rr < 4; ++rr) {
                float v = acc[i][j][rr] + bv;
                if (RELU) v = fmaxf(v, 0.f);
                const int r = rbase + rr;
                long oidx;
                if (GXMODE) { const int tt = r & 2047, bb = r >> 11; oidx = (long)(tt * 16 + bb) * N + c; }
                else        { oidx = (long)r * N + c; }
                if (OUTF32) ((float*)Cv)[oidx] = v;
                else        ((bf16*)Cv)[oidx]  = (bf16)v;
            }
        }
    }
}

// ---------------- GRU scan: 56 persistent single-wave WGs ----------------
// One wave per WG handles its 16 cols x ALL 3 gates: 84 MFMAs, Whh slice in
// 336 VGPRs.  MFMA C-layout (col=lane&15, row=(lane>>4)*4+reg) puts r,z,n for
// a given (batch,col) in the SAME lane/reg -> no LDS, no __syncthreads at all.
// h broadcast: hbuf[2][16][896] bf16, published via agent-scope u32 atomic
// stores (write-through to LLC), flag after raw vmcnt(0) drain.
__global__ __launch_bounds__(64, 1) void gru_scan(const bf16* __restrict__ Whh,
                                                  const float* __restrict__ bhh,
                                                  const bf16* __restrict__ gx,
                                                  bf16* __restrict__ hs,
                                                  bf16* __restrict__ hbuf,
                                                  unsigned int* __restrict__ flags)
{
    const int lane = threadIdx.x;       // 0..63
    const int n16  = lane & 15;
    const int quad = lane >> 4;
    const int wg   = blockIdx.x;
    const int col0 = wg * 16;
    const int c    = col0 + n16;

    // one-time: Whh slice (3 gates x 16 cols x 896) -> 84 bf16x8 in VGPRs.
    // B-frag: n=lane&15 selects W row (gate col), k=quad*8+j.
    bf16x8 wfr[28], wfz[28], wfn[28];
    {
        const bf16* w0 = Whh + (long)(0 * 896 + c) * 896 + quad * 8;
        const bf16* w1 = Whh + (long)(1 * 896 + c) * 896 + quad * 8;
        const bf16* w2 = Whh + (long)(2 * 896 + c) * 896 + quad * 8;
#pragma unroll
        for (int kt = 0; kt < 28; ++kt) {
            wfr[kt] = *(const bf16x8*)(w0 + kt * 32);
            wfz[kt] = *(const bf16x8*)(w1 + kt * 32);
            wfn[kt] = *(const bf16x8*)(w2 + kt * 32);
        }
    }
    const float bhr = bhh[0 * 896 + c];
    const float bhz = bhh[1 * 896 + c];
    const float bhn = bhh[2 * 896 + c];

    // per-lane state: h for (batches quad*4+rr, col c), f32
    float hl[4] = {0.f, 0.f, 0.f, 0.f};

    // gx prefetch for t=0: gxv[g*4+rr]
    float gxv[12];
#pragma unroll
    for (int g = 0; g < 3; ++g)
#pragma unroll
        for (int rr = 0; rr < 4; ++rr)
            gxv[g * 4 + rr] = (float)gx[(long)(quad * 4 + rr) * 2688 + g * 896 + c];

    for (int t = 0; t < 2048; ++t) {
        const bf16* hb_cur  = hbuf + (t & 1) * (16 * 896);
        bf16*       hb_next = hbuf + ((t + 1) & 1) * (16 * 896);

        // 1) spin until all 56 WGs have published h_t (one flag per lane)
        if (t > 0) {
            for (;;) {
                unsigned f = (lane < NWG)
                    ? __hip_atomic_load(flags + lane * 32, __ATOMIC_RELAXED, __HIP_MEMORY_SCOPE_AGENT)
                    : 0xFFFFFFFFu;
                if (__all(f >= (unsigned)t)) break;
                __builtin_amdgcn_s_sleep(1);
            }
        }
        // acquire: invalidate stale L1/L2 so h loads come from LLC
        __builtin_amdgcn_fence(__ATOMIC_ACQUIRE, "agent");

        // 2) gh = h @ Whh_slice^T for all 3 gates; A-frag read directly from
        //    global hbuf (row b=n16, k=quad*8), shared across the 3 MFMAs.
        floatx4 ar = {0.f, 0.f, 0.f, 0.f};
        floatx4 az = {0.f, 0.f, 0.f, 0.f};
        floatx4 an = {0.f, 0.f, 0.f, 0.f};
        const bf16* hrow = hb_cur + n16 * 896 + quad * 8;
#pragma unroll
        for (int kt = 0; kt < 28; ++kt) {
            bf16x8 af = *(const bf16x8*)(hrow + kt * 32);
            ar = __builtin_amdgcn_mfma_f32_16x16x32_bf16(af, wfr[kt], ar, 0, 0, 0);
            az = __builtin_amdgcn_mfma_f32_16x16x32_bf16(af, wfz[kt], az, 0, 0, 0);
            an = __builtin_amdgcn_mfma_f32_16x16x32_bf16(af, wfn[kt], an, 0, 0, 0);
        }

        // 3) gate nonlinearity + h update, fully in-lane (4 batches x 1 col)
        float hn[4];
#pragma unroll
        for (int rr = 0; rr < 4; ++rr) {
            const float rg = sigm(gxv[0 + rr] + ar[rr] + bhr);
            const float zg = sigm(gxv[4 + rr] + az[rr] + bhz);
            const float ng = fast_tanh(gxv[8 + rr] + rg * (an[rr] + bhn));
            hn[rr] = (1.f - zg) * ng + zg * hl[rr];
            hl[rr] = hn[rr];
        }

        // 4) publish h_{t+1}: pair-pack cols (c, c^1) via shfl_xor into u32,
        //    agent-scope write-through stores (even lanes rr 0-1, odd rr 2-3)
        {
            unsigned pk[4];
#pragma unroll
            for (int rr = 0; rr < 4; ++rr) {
                const float p  = __shfl_xor(hn[rr], 1);
                const float lo = (n16 & 1) ? p : hn[rr];
                const float hi = (n16 & 1) ? hn[rr] : p;
                pk[rr] = pack_bf2(lo, hi);
            }
            const int ceven = col0 + (n16 & ~1);
            unsigned int* hb32 = (unsigned int*)hb_next;
            const int rs = (n16 & 1) ? 2 : 0;
#pragma unroll
            for (int k = 0; k < 2; ++k) {
                const int b = quad * 4 + rs + k;
                __hip_atomic_store(hb32 + ((b * 896 + ceven) >> 1), pk[rs + k],
                                   __ATOMIC_RELAXED, __HIP_MEMORY_SCOPE_AGENT);
            }
        }
        // drain wave's stores (and the hbuf loads -> parity ping-pong safe),
        // then release the flag.  No wbl2: data already at LLC (sc-stores).
        asm volatile("s_waitcnt vmcnt(0)" ::: "memory");
        if (lane == 0)
            __hip_atomic_store(flags + wg * 32, (unsigned)(t + 1),
                               __ATOMIC_RELAXED, __HIP_MEMORY_SCOPE_AGENT);

        // 5) off critical path: hs store (nontemporal) + gx prefetch for t+1
#pragma unroll
        for (int rr = 0; rr < 4; ++rr) {
            const long hidx = ((long)(quad * 4 + rr) * 2048 + t) * 896 + c;
            __builtin_nontemporal_store(bf_bits(hn[rr]), (unsigned short*)(hs + hidx));
        }
        const int tn_ = (t + 1 < 2048) ? (t + 1) : 2047;
#pragma unroll
        for (int g = 0; g < 3; ++g)
#pragma unroll
            for (int rr = 0; rr < 4; ++rr)
                gxv[g * 4 + rr] = (float)gx[(long)(tn_ * 16 + quad * 4 + rr) * 2688 + g * 896 + c];
    }
}

extern "C" void kernel_launch(void* const* d_in, const int* in_sizes, int n_in,
                              void* d_out, int out_size, void* d_ws, size_t ws_size,
                              hipStream_t stream)
{
    const int*   samp = (const int*)d_in[0];
    const float* cnd  = (const float*)d_in[1];
    const float* emb  = (const float*)d_in[2];
    const float* Wih  = (const float*)d_in[3];
    const float* bih  = (const float*)d_in[4];
    const float* Whh  = (const float*)d_in[5];
    const float* bhh  = (const float*)d_in[6];
    const float* fc1w = (const float*)d_in[7];
    const float* fc1b = (const float*)d_in[8];
    const float* fc2w = (const float*)d_in[9];
    const float* fc2b = (const float*)d_in[10];

    char* ws = (char*)d_ws;
    unsigned int* flags = (unsigned int*)(ws + FL_OFF);
    bf16* hbuf = (bf16*)(ws + HB_OFF);
    bf16* wbf  = (bf16*)(ws + WBF_OFF);
    bf16* gx   = (bf16*)(ws + GX_OFF);
    bf16* hs   = (bf16*)(ws + HSX_OFF);
    bf16* x    = (bf16*)(ws + HSX_OFF);   // x dead before hs written
    bf16* h1   = (bf16*)(ws + GX_OFF);    // h1 aliases gx (dead after scan)

    bf16* wih_bf = wbf;
    bf16* whh_bf = wbf + W_IH_E;
    bf16* fc1_bf = whh_bf + W_HH_E;
    bf16* fc2_bf = fc1_bf + W_F1_E;

    (void)hipMemsetAsync(flags, 0, 8192, stream);    // barrier flags
    (void)hipMemsetAsync(hbuf, 0, 57344, stream);    // h0 = 0 (both parities)

    // 0) weights f32 -> bf16
    k_cvt<<<1176, 256, 0, stream>>>(Wih,  wih_bf);
    k_cvt<<<1176, 256, 0, stream>>>(Whh,  whh_bf);
    k_cvt<<< 448, 256, 0, stream>>>(fc1w, fc1_bf);
    k_cvt<<< 512, 256, 0, stream>>>(fc2w, fc2_bf);

    // 1) x = concat(emb[sample], cnd)  f32->bf16   [32768, 896]
    k_embed<<<14336, 256, 0, stream>>>(samp, cnd, emb, x);
    // 2) gx = x @ W_ih^T + b_ih  -> [T][B][2688] layout (bf16)
    gemm_bt<0, 1, 0><<<dim3(21, 256), 256, 0, stream>>>(x, wih_bf, bih, gx, 32768, 2688, 896);
    // 3) sequential GRU scan -> hs [B][T][896] (bf16)
    gru_scan<<<NWG, 64, 0, stream>>>(whh_bf, bhh, gx, hs, hbuf, flags);
    // 4) h1 = relu(hs @ fc1_w^T + fc1_b)           [32768, 1024] (bf16)
    gemm_bt<1, 0, 0><<<dim3(8, 256), 256, 0, stream>>>(hs, fc1_bf, fc1b, h1, 32768, 1024, 896);
    // 5) out = h1 @ fc2_w^T + fc2_b                [32768, 1024] -> f32 d_out
    gemm_bt<0, 0, 1><<<dim3(8, 256), 256, 0, stream>>>(h1, fc2_bf, fc2b, d_out, 32768, 1024, 1024);
}